// Round 5
// baseline (21459.785 us; speedup 1.0000x reference)
//
#include <hip/hip_runtime.h>
#include <hip/hip_bf16.h>
#include <math.h>

typedef __hip_bfloat16 bf16;
using short4v = __attribute__((ext_vector_type(4))) short;
using short8 = __attribute__((ext_vector_type(8))) short;
using f32x4  = __attribute__((ext_vector_type(4))) float;

#define E_ 320
#define K_ 128
#define H_ 10
#define HD_ 32
#define T_ 256
#define TM1_ 255
#define SMAX_ (TM1_*K_)      // 32640
#define MAXCH_ 30
#define QSCALE 0.17677669529663687f
#define EPS_LN 1e-5f

// ---- dtype-agnostic input load: isbf ? bf16 : f32 ----
__device__ __forceinline__ float ldin(const void* p, size_t i, int isbf){
  if (isbf) return __bfloat162float(((const bf16*)p)[i]);
  return ((const float*)p)[i];
}
__device__ __forceinline__ void stout(void* p, size_t i, float v, int isbf){
  if (isbf) ((bf16*)p)[i] = __float2bfloat16(v);
  else      ((float*)p)[i] = v;
}

// block = 320 threads (5 waves). Reduces a and b across the block.
__device__ __forceinline__ void reduce2_320(float& a, float& b, float* sc){
  #pragma unroll
  for (int off = 32; off > 0; off >>= 1){
    a += __shfl_down(a, off, 64);
    b += __shfl_down(b, off, 64);
  }
  int w = threadIdx.x >> 6, lane = threadIdx.x & 63;
  __syncthreads();
  if (lane == 0){ sc[w] = a; sc[8+w] = b; }
  __syncthreads();
  a = sc[0]+sc[1]+sc[2]+sc[3]+sc[4];
  b = sc[8]+sc[9]+sc[10]+sc[11]+sc[12];
}

// ---------------- dtype detector ----------------
__global__ void detect_kernel(const void* __restrict__ mu0, int* __restrict__ flag){
  int lane = threadIdx.x;
  const unsigned short* u = (const unsigned short*)mu0;
  int cnt = 0;
  #pragma unroll
  for (int rep = 0; rep < 2; ++rep){
    unsigned short w = u[(size_t)(lane + rep*64) * 2];
    float v = __uint_as_float(((unsigned int)w) << 16);
    float a = fabsf(v);
    if (a >= 1e-4f && a <= 64.f) cnt++;
  }
  #pragma unroll
  for (int off = 32; off > 0; off >>= 1) cnt += __shfl_down(cnt, off, 64);
  if (lane == 0) *flag = (cnt >= 64) ? 1 : 0;
}

// ---------------- setup: fused projection weights (bf16, [n][k] layout) ----------------
// WcB[(sec*320+o)*320 + i] = s(sec) * sum_m in_proj_w[sec*320+o][m] * qkv_w[sec*320+m][i]
__global__ __launch_bounds__(256) void setup_wc(const void* __restrict__ inw,
                                                const void* __restrict__ qkvw,
                                                bf16* __restrict__ WcB,
                                                const int* __restrict__ flagp){
  const int isbf = *flagp;
  int sec = blockIdx.z;
  int i = blockIdx.y*16 + threadIdx.y;   // contraction dim k
  int o = blockIdx.x*16 + threadIdx.x;   // output col within section
  __shared__ float As[16][17];
  __shared__ float Bs[16][17];
  float acc = 0.f;
  for (int mt = 0; mt < E_; mt += 16){
    As[threadIdx.y][threadIdx.x] = ldin(inw, ((size_t)(sec*E_ + blockIdx.x*16 + threadIdx.x))*E_ + mt + threadIdx.y, isbf);
    Bs[threadIdx.y][threadIdx.x] = ldin(qkvw, ((size_t)(sec*E_ + mt + threadIdx.x))*E_ + blockIdx.y*16 + threadIdx.y, isbf);
    __syncthreads();
    #pragma unroll
    for (int mm = 0; mm < 16; ++mm) acc += Bs[threadIdx.y][mm] * As[mm][threadIdx.x];
    __syncthreads();
  }
  if (sec == 0) acc *= QSCALE;
  WcB[((size_t)(sec*E_ + o))*E_ + i] = __float2bfloat16(acc);
}

// bc[c]; owB = bf16 copy of out_w ([n][k] row-major = as-is); vec = f32 outb|lng|lnb
__global__ __launch_bounds__(256) void setup_misc(const void* __restrict__ inw,
                                                  const void* __restrict__ inb,
                                                  const void* __restrict__ qkvb,
                                                  const void* __restrict__ outw,
                                                  const void* __restrict__ outb,
                                                  const void* __restrict__ lng,
                                                  const void* __restrict__ lnb,
                                                  float* __restrict__ bc,
                                                  bf16* __restrict__ owB,
                                                  float* __restrict__ vec,
                                                  const int* __restrict__ flagp){
  const int isbf = *flagp;
  int id = blockIdx.x*256 + threadIdx.x;
  if (id < 960){
    int sec = id / E_, o = id % E_;
    float acc = 0.f;
    for (int m = 0; m < E_; ++m)
      acc += ldin(inw, ((size_t)(sec*E_+o))*E_ + m, isbf) * ldin(qkvb, sec*E_ + m, isbf);
    acc += ldin(inb, id, isbf);
    if (sec == 0) acc *= QSCALE;
    bc[id] = acc;
  }
  int j = id - 1024;
  if (j >= 0 && j < E_*E_){
    owB[j] = __float2bfloat16(ldin(outw, j, isbf));
  }
  int v = id - (1024 + E_*E_);
  if (v >= 0 && v < 960){
    if (v < 320)       vec[v] = ldin(outb, v, isbf);
    else if (v < 640)  vec[v] = ldin(lng, v - 320, isbf);
    else               vec[v] = ldin(lnb, v - 640, isbf);
  }
}

// ---------------- alpha0 = LN(mu_0_alpha) ----------------
__global__ __launch_bounds__(320) void ln0_kernel(const void* __restrict__ mu0,
                                                  const float* __restrict__ vec,
                                                  float* __restrict__ alpha,
                                                  void* __restrict__ out,
                                                  const int* __restrict__ flagp){
  const int isbf = *flagp;
  int r = blockIdx.x, c = threadIdx.x;
  __shared__ float sc[16];
  float x = ldin(mu0, (size_t)r*E_ + c, isbf);
  float s = x, s2 = x*x;
  reduce2_320(s, s2, sc);
  float mean = s * (1.f/E_);
  float var  = s2 * (1.f/E_) - mean*mean;
  float y = (x - mean) * rsqrtf(var + EPS_LN) * vec[320 + c] + vec[640 + c];
  alpha[(size_t)r*E_ + c] = y;
  stout(out, (size_t)r*E_ + c, y, isbf);
}

// ---------------- fused combine(t-1) + LN + project(t) ----------------
// grid (3 col-groups, 8 row-groups), block 512 = 8 waves. Row-group rg owns rows 16rg..16rg+15.
// All 3 col-groups redundantly do merge+out-proj+LN (identical result); cg0 writes alpha/out.
// Then each col-group projects its 320 of the 960 output cols (q2 / K / V^T).
// mfma_f32_16x16x32_bf16: A[m=lane&15][k=quad*8+j], B[k=quad*8+j][n=lane&15],
//                         C[row=quad*4+r][col=lane&15].
__global__ __launch_bounds__(512) void cp_kernel(const float* __restrict__ part,
                                                 const bf16* __restrict__ owB,
                                                 const bf16* __restrict__ WcB,
                                                 const float* __restrict__ bc,
                                                 const float* __restrict__ vec,
                                                 const float* __restrict__ ain,
                                                 float* __restrict__ aout,
                                                 void* __restrict__ out,
                                                 const int* __restrict__ flagp,
                                                 bf16* __restrict__ q2b,
                                                 bf16* __restrict__ kcb,
                                                 bf16* __restrict__ vtb,
                                                 int t, int nch, int do_combine, int do_project){
  const int isbf = *flagp;
  int cg = blockIdx.x;          // 0..2
  int rg = blockIdx.y;          // 0..7
  int r0 = rg*16;
  int tid = threadIdx.x;
  int w = tid >> 6, lane = tid & 63, cn = lane & 15, quad = lane >> 4;

  __shared__ bf16  af[16][328];    // merged attention output (bf16) as A operand
  __shared__ float xbuf[16][328];  // post-outproj + bias + residual (f32)
  __shared__ bf16  a2[16][328];    // post-LN alpha (bf16) as A operand
  __shared__ float mlw[16][10][MAXCH_];
  __shared__ float mlL[16][10];

  if (do_combine){
    // --- merge softmax partials ---
    if (tid < 160){
      int r = tid / 10, h = tid % 10;
      float mst = -INFINITY;
      for (int ci = 0; ci < nch; ++ci)
        mst = fmaxf(mst, part[(((size_t)h*MAXCH_ + ci)*K_ + r0 + r)*36 + 32]);
      float L = 0.f;
      for (int ci = 0; ci < nch; ++ci){
        size_t base = (((size_t)h*MAXCH_ + ci)*K_ + r0 + r)*36;
        float wgt = __expf(part[base + 32] - mst);
        mlw[r][h][ci] = wgt;
        L += wgt * part[base + 33];
      }
      mlL[r][h] = L;
    }
    __syncthreads();
    for (int v = tid; v < 16*E_; v += 512){
      int r = v / E_, e = v % E_;
      int h = e >> 5, d = e & 31;
      float acc = 0.f;
      for (int ci = 0; ci < nch; ++ci)
        acc += mlw[r][h][ci] * part[(((size_t)h*MAXCH_ + ci)*K_ + r0 + r)*36 + d];
      af[r][e] = __float2bfloat16(acc / mlL[r][h]);
    }
    __syncthreads();

    // --- out-proj MFMA: C(16x320) = af(16x320) . out_w^T ---
    {
      f32x4 acc[3]; int ntv[3]; int ntc = 0;
      for (int nt = w; nt < 20; nt += 8){ ntv[ntc] = nt; acc[ntc] = (f32x4){0.f,0.f,0.f,0.f}; ntc++; }
      for (int kk = 0; kk < 10; ++kk){
        short8 afr = *(const short8*)(const void*)(&af[cn][kk*32 + quad*8]);
        for (int i = 0; i < ntc; ++i){
          short8 bfr = *(const short8*)(const void*)(owB + ((size_t)(ntv[i]*16 + cn))*E_ + kk*32 + quad*8);
          acc[i] = __builtin_amdgcn_mfma_f32_16x16x32_bf16(afr, bfr, acc[i], 0, 0, 0);
        }
      }
      for (int i = 0; i < ntc; ++i){
        int col = ntv[i]*16 + cn;
        #pragma unroll
        for (int rr = 0; rr < 4; ++rr){
          int lr = quad*4 + rr;
          xbuf[lr][col] = acc[i][rr] + vec[col] + ain[(size_t)(r0+lr)*E_ + col];
        }
      }
    }
    __syncthreads();

    // --- LN per row ---
    {
      int lr = tid >> 5;         // 0..15
      int j32 = tid & 31;
      float s = 0.f, s2 = 0.f;
      for (int c = j32; c < E_; c += 32){ float x = xbuf[lr][c]; s += x; s2 += x*x; }
      #pragma unroll
      for (int off = 1; off < 32; off <<= 1){
        s  += __shfl_xor(s, off, 32);
        s2 += __shfl_xor(s2, off, 32);
      }
      float mean = s * (1.f/E_);
      float var  = s2 * (1.f/E_) - mean*mean;
      float rs = rsqrtf(var + EPS_LN);
      for (int c = j32; c < E_; c += 32){
        float y = (xbuf[lr][c] - mean) * rs * vec[320 + c] + vec[640 + c];
        a2[lr][c] = __float2bfloat16(y);
        if (cg == 0){
          aout[(size_t)(r0+lr)*E_ + c] = y;
          stout(out, ((size_t)t*K_ + r0 + lr)*E_ + c, y, isbf);
        }
      }
    }
    __syncthreads();
  } else {
    // t == 0: alpha comes straight from ln0
    for (int v = tid; v < 16*E_; v += 512){
      int r = v / E_, e = v % E_;
      a2[r][e] = __float2bfloat16(ain[(size_t)(r0+r)*E_ + e]);
    }
    __syncthreads();
  }

  if (!do_project) return;

  // --- project MFMA: P(16 x 320cols-of-this-cg) = a2(16x320) . Wc ---
  {
    f32x4 acc[3]; int ntv[3]; int ntc = 0;
    for (int nt = w; nt < 20; nt += 8){ ntv[ntc] = nt; acc[ntc] = (f32x4){0.f,0.f,0.f,0.f}; ntc++; }
    for (int kk = 0; kk < 10; ++kk){
      short8 afr = *(const short8*)(const void*)(&a2[cn][kk*32 + quad*8]);
      for (int i = 0; i < ntc; ++i){
        short8 bfr = *(const short8*)(const void*)(WcB + ((size_t)(cg*E_ + ntv[i]*16 + cn))*E_ + kk*32 + quad*8);
        acc[i] = __builtin_amdgcn_mfma_f32_16x16x32_bf16(afr, bfr, acc[i], 0, 0, 0);
      }
    }
    for (int i = 0; i < ntc; ++i){
      int coll = ntv[i]*16 + cn;
      float bias = bc[cg*E_ + coll];
      if (cg == 0){
        #pragma unroll
        for (int rr = 0; rr < 4; ++rr)
          q2b[(size_t)(r0 + quad*4 + rr)*E_ + coll] = __float2bfloat16(acc[i][rr] + bias);
      } else if (cg == 1){
        #pragma unroll
        for (int rr = 0; rr < 4; ++rr)
          kcb[((size_t)(t*K_ + r0 + quad*4 + rr))*E_ + coll] = __float2bfloat16(acc[i][rr] + bias);
      } else {
        union { short4v v; bf16 e[4]; } u;
        #pragma unroll
        for (int rr = 0; rr < 4; ++rr) u.e[rr] = __float2bfloat16(acc[i][rr] + bias);
        *(short4v*)(void*)(vtb + (size_t)coll*SMAX_ + t*K_ + r0 + quad*4) = u.v;
      }
    }
  }
}

// ---------------- per-step: MFMA flash-attention partials (transposed S) ----------------
// grid (nchU, H). block 512 = 8 waves; wave w owns q-tile w (q rows 16w..16w+15).
__global__ __launch_bounds__(512) void attn_mfma(const bf16* __restrict__ q2b,
                                                 const bf16* __restrict__ kcb,
                                                 const bf16* __restrict__ vtb,
                                                 float* __restrict__ part,
                                                 int S, int chunkS){
  int ci = blockIdx.x, h = blockIdx.y;
  int w    = threadIdx.x >> 6;
  int lane = threadIdx.x & 63;
  int cn   = lane & 15;
  int quad = lane >> 4;
  __shared__ bf16 pbuf[8][16][40];

  int s0 = ci*chunkS, s1 = min(s0 + chunkS, S);

  short8 qf = *(const short8*)(const void*)(q2b + (size_t)(w*16 + cn)*E_ + h*HD_ + quad*8);

  f32x4 accT[2];
  accT[0] = (f32x4){0.f,0.f,0.f,0.f};
  accT[1] = (f32x4){0.f,0.f,0.f,0.f};
  float mcol = -INFINITY, lcol = 0.f;

  for (int sb = s0; sb < s1; sb += 32){
    short8 kf0 = *(const short8*)(const void*)(kcb + (size_t)(sb +      cn)*E_ + h*HD_ + quad*8);
    short8 kf1 = *(const short8*)(const void*)(kcb + (size_t)(sb + 16 + cn)*E_ + h*HD_ + quad*8);
    short8 vf0 = *(const short8*)(const void*)(vtb + (size_t)(h*HD_ +      cn)*SMAX_ + sb + quad*8);
    short8 vf1 = *(const short8*)(const void*)(vtb + (size_t)(h*HD_ + 16 + cn)*SMAX_ + sb + quad*8);
    f32x4 z = (f32x4){0.f,0.f,0.f,0.f};
    f32x4 sT0 = __builtin_amdgcn_mfma_f32_16x16x32_bf16(kf0, qf, z, 0, 0, 0);
    f32x4 sT1 = __builtin_amdgcn_mfma_f32_16x16x32_bf16(kf1, qf, z, 0, 0, 0);

    float mx = fmaxf(fmaxf(fmaxf(sT0[0], sT0[1]), fmaxf(sT0[2], sT0[3])),
                     fmaxf(fmaxf(sT1[0], sT1[1]), fmaxf(sT1[2], sT1[3])));
    mx = fmaxf(mx, __shfl_xor(mx, 16, 64));
    mx = fmaxf(mx, __shfl_xor(mx, 32, 64));
    float mn = fmaxf(mcol, mx);
    float corr = __expf(mcol - mn);
    mcol = mn;

    float p0[4], p1[4];
    #pragma unroll
    for (int r = 0; r < 4; ++r){ p0[r] = __expf(sT0[r] - mn); p1[r] = __expf(sT1[r] - mn); }
    float ps = (p0[0]+p0[1]) + (p0[2]+p0[3]) + (p1[0]+p1[1]) + (p1[2]+p1[3]);
    ps += __shfl_xor(ps, 16, 64);
    ps += __shfl_xor(ps, 32, 64);
    lcol = lcol*corr + ps;
    accT[0] *= corr;
    accT[1] *= corr;

    union { short4v v; bf16 e[4]; } u0, u1;
    #pragma unroll
    for (int r = 0; r < 4; ++r){ u0.e[r] = __float2bfloat16(p0[r]); u1.e[r] = __float2bfloat16(p1[r]); }
    *(short4v*)(void*)(&pbuf[w][cn][quad*4])      = u0.v;
    *(short4v*)(void*)(&pbuf[w][cn][16 + quad*4]) = u1.v;
    asm volatile("s_waitcnt lgkmcnt(0)" ::: "memory");
    short8 pf = *(const short8*)(const void*)(&pbuf[w][cn][quad*8]);
    accT[0] = __builtin_amdgcn_mfma_f32_16x16x32_bf16(vf0, pf, accT[0], 0, 0, 0);
    accT[1] = __builtin_amdgcn_mfma_f32_16x16x32_bf16(vf1, pf, accT[1], 0, 0, 0);
  }

  size_t base = (((size_t)h*MAXCH_ + ci)*K_ + 16*w + cn)*36;
  *(f32x4*)(part + base + quad*4)      = accT[0];
  *(f32x4*)(part + base + 16 + quad*4) = accT[1];
  if (quad == 0){ part[base + 32] = mcol; part[base + 33] = lcol; }
}

extern "C" void kernel_launch(void* const* d_in, const int* in_sizes, int n_in,
                              void* d_out, int out_size, void* d_ws, size_t ws_size,
                              hipStream_t stream){
  const void* mu0  = d_in[0];
  const void* qkvw = d_in[1];
  const void* qkvb = d_in[2];
  const void* inw  = d_in[3];
  const void* inb  = d_in[4];
  const void* outw = d_in[5];
  const void* outb = d_in[6];
  const void* lng  = d_in[7];
  const void* lnb  = d_in[8];
  float* ws = (float*)d_ws;

  // ws layout (float offsets), all 16B-aligned
  const size_t O_WCB    = 0;         // 960x320 bf16 = 153600 floats
  const size_t O_OWB    = 153600;    // 320x320 bf16 = 51200 floats
  const size_t O_BC     = 204800;    // 1024
  const size_t O_VEC    = 205824;    // 1024
  const size_t O_ALPHA0 = 206848;    // 40960
  const size_t O_ALPHA1 = 247808;    // 40960
  const size_t O_PART   = 288768;    // 10*30*128*36 = 1382400
  const size_t O_FLAG   = 1671168;   // 32
  const size_t O_Q2     = 1671200;   // 128*320 bf16 = 20480 floats
  const size_t O_KC     = 1691680;   // SMAX*320 bf16 = 5222400 floats
  const size_t O_VT     = 6914080;   // SMAX*320 bf16 = 5222400 floats
  // end = 12136480 floats = 48.5 MB

  bf16*  WcB   = (bf16*)(ws + O_WCB);
  bf16*  owB   = (bf16*)(ws + O_OWB);
  float* bc    = ws + O_BC;
  float* vec   = ws + O_VEC;
  float* abuf0 = ws + O_ALPHA0;
  float* abuf1 = ws + O_ALPHA1;
  float* part  = ws + O_PART;
  int*   flag  = (int*)(ws + O_FLAG);
  bf16*  q2b   = (bf16*)(ws + O_Q2);
  bf16*  kcb   = (bf16*)(ws + O_KC);
  bf16*  vtb   = (bf16*)(ws + O_VT);

  detect_kernel<<<dim3(1), dim3(64), 0, stream>>>(mu0, flag);
  setup_wc<<<dim3(20,20,3), dim3(16,16), 0, stream>>>(inw, qkvw, WcB, flag);
  setup_misc<<<dim3(408), dim3(256), 0, stream>>>(inw, inb, qkvb, outw, outb, lng, lnb, bc, owB, vec, flag);
  ln0_kernel<<<dim3(128), dim3(320), 0, stream>>>(mu0, vec, abuf0, d_out, flag);

  int nch_prev = 0;
  for (int t = 0; t < TM1_; ++t){
    // alpha(k) lives in abuf[k&1]; cp(t) reads alpha(t-1) (or alpha(0) at t=0), writes alpha(t)
    float* ain  = (t == 0) ? abuf0 : ((t & 1) ? abuf0 : abuf1);
    float* aout = (t & 1) ? abuf1 : abuf0;
    cp_kernel<<<dim3(3,8), dim3(512), 0, stream>>>(part, owB, WcB, bc, vec, ain, aout,
                                                   d_out, flag, q2b, kcb, vtb,
                                                   t, nch_prev, (t > 0) ? 1 : 0, 1);
    int S = (t+1)*K_;
    int nch = (S + 255) / 256; if (nch > MAXCH_) nch = MAXCH_;
    int chunkS = (((S + nch - 1)/nch) + 127) / 128 * 128;
    int nchU = (S + chunkS - 1) / chunkS;
    attn_mfma<<<dim3(nchU, H_), dim3(512), 0, stream>>>(q2b, kcb, vtb, part, S, chunkS);
    nch_prev = nchU;
  }
  // final combine (produces alpha(255) -> out rows 255*K)
  {
    int t = TM1_;
    float* ain  = (t & 1) ? abuf0 : abuf1;
    float* aout = (t & 1) ? abuf1 : abuf0;
    cp_kernel<<<dim3(3,8), dim3(512), 0, stream>>>(part, owB, WcB, bc, vec, ain, aout,
                                                   d_out, flag, q2b, kcb, vtb,
                                                   t, nch_prev, 1, 0);
  }
}